// Round 12
// baseline (433.993 us; speedup 1.0000x reference)
//
#include <hip/hip_runtime.h>
#include <hip/hip_bf16.h>
#include <math.h>

namespace {

constexpr int B = 32, N = 125, D = 256, H = 8, HD = 32, FF = 1024,
              E = 5, V = 32000, HID = 128, S = 128, MAXPOS = 512;
constexpr int BSD = B * S * D;     // 1,048,576
constexpr int BSF = B * S * FF;    // 4,194,304
constexpr float EPS = 1e-12f;
constexpr float THRESH = 0.7f;

// per-expert G-format weight block: Gq|Gk|Gv|Go|Gf1|Gf2 (shorts)
constexpr size_t GW_Q = 0, GW_K = 65536, GW_V = 131072, GW_O = 196608,
                 GW_F1 = 262144, GW_F2 = 524288, GW_STRIDE = 786432;

typedef __attribute__((ext_vector_type(4))) float f32x4;
typedef __attribute__((ext_vector_type(8))) short short8v;

__device__ __forceinline__ short f2bf(float f) {
  __hip_bfloat16 h = __float2bfloat16(f);  // RNE
  short s;
  __builtin_memcpy(&s, &h, 2);
  return s;
}

__device__ __forceinline__ float bf2f(short s) {
  unsigned int u = ((unsigned int)(unsigned short)s) << 16;
  float f;
  __builtin_memcpy(&f, &u, 4);
  return f;
}

__device__ __forceinline__ float gelu_exact(float x) {
  return 0.5f * x * (1.f + erff(x * 0.70710678118654752f));
}

__device__ __forceinline__ float wave_sum64(float v) {
#pragma unroll
  for (int off = 32; off > 0; off >>= 1) v += __shfl_xor(v, off);
  return v;
}

// async global->LDS, 16B per lane; lds dest = wave-uniform base + lane*16
__device__ __forceinline__ void gload16(const void* g, void* l) {
  __builtin_amdgcn_global_load_lds(
      (const __attribute__((address_space(1))) unsigned int*)g,
      (__attribute__((address_space(3))) unsigned int*)l, 16, 0, 0);
}

// ---------------- router ----------------
__global__ __launch_bounds__(HID) void router1_kernel(
    const float* __restrict__ h_t, const float* __restrict__ e_task,
    const float* __restrict__ e_layout, const float* __restrict__ W1,
    const float* __restrict__ b1, const float* __restrict__ W2,
    const float* __restrict__ b2, const float* __restrict__ hintW,
    const float* __restrict__ hintb, float* __restrict__ gp_ws,
    float* __restrict__ gp_out) {
  int b = blockIdx.x;
  int t = threadIdx.x;
  float acc = b1[t];
  const float* rows[3] = {h_t + b * D, e_task + b * D, e_layout + b * D};
  for (int seg = 0; seg < 3; ++seg) {
    const float* r = rows[seg];
    const float* w = W1 + (size_t)seg * D * HID;
    for (int i = 0; i < D; ++i) acc += r[i] * w[i * HID + t];
  }
  __shared__ float hid[HID];
  __shared__ float logits[E];
  hid[t] = fmaxf(acc, 0.f);
  __syncthreads();
  if (t < E) {
    float l = b2[t] + hintb[t];
    for (int hh = 0; hh < HID; ++hh) l += hid[hh] * W2[hh * E + t];
    const float* el = e_layout + b * D;
    for (int dd = 0; dd < D; ++dd) l += el[dd] * hintW[dd * E + t];
    logits[t] = l;
  }
  __syncthreads();
  if (t == 0) {
    float mx = logits[0];
    for (int e2 = 1; e2 < E; ++e2) mx = fmaxf(mx, logits[e2]);
    float p[E];
    float se = 0.f;
    for (int e2 = 0; e2 < E; ++e2) {
      p[e2] = expf(logits[e2] - mx);
      se += p[e2];
    }
    float inv = 1.f / se;
    for (int e2 = 0; e2 < E; ++e2) {
      float pe = p[e2] * inv;
      gp_ws[b * E + e2] = pe;
      gp_out[b * E + e2] = pe;
    }
  }
}

__global__ __launch_bounds__(64) void router2_kernel(
    const float* __restrict__ gp, const int* __restrict__ topk_ptr,
    float* __restrict__ comb) {
  __shared__ int allk1;
  int t = threadIdx.x;
  if (t == 0) allk1 = 1;
  __syncthreads();
  float p[E];
  if (t < B) {
    float mx = 0.f;
    for (int e2 = 0; e2 < E; ++e2) {
      p[e2] = gp[t * E + e2];
      mx = fmaxf(mx, p[e2]);
    }
    if (!(mx > THRESH)) allk1 = 0;  // benign race: all writers store 0
  }
  __syncthreads();
  int k1 = allk1;
  if (t < B) {
    for (int e2 = 0; e2 < E; ++e2) comb[t * E + e2] = 0.f;
    int tk = *topk_ptr;
    if (tk > E) tk = E;
    float q[E];
    for (int e2 = 0; e2 < E; ++e2) q[e2] = p[e2];
    for (int kk = 0; kk < tk; ++kk) {
      int bi = 0;
      float bv = q[0];
      for (int e2 = 1; e2 < E; ++e2)
        if (q[e2] > bv) { bv = q[e2]; bi = e2; }
      float w = (kk == 0) ? bv : (k1 ? 0.f : bv);
      comb[t * E + bi] += w;
      q[bi] = -1.f;
    }
  }
}

// ---------------- weight pre-pass: W[K][Nc] f32 -> G[Nc][K] bf16 swizzled --
__device__ __forceinline__ void prep_body(const float* __restrict__ Wp,
                                          short* __restrict__ Gp, int K,
                                          int Nc) {
  __shared__ float Wl[64][65];
  int t = threadIdx.x;
  int n0 = blockIdx.x * 64, k0 = blockIdx.y * 64;
#pragma unroll
  for (int p = 0; p < 4; ++p) {
    int krow = p * 16 + (t >> 4);
    int nc = (t & 15) * 4;
    float4 v = *reinterpret_cast<const float4*>(
        Wp + (size_t)(k0 + krow) * Nc + n0 + nc);
    Wl[krow][nc] = v.x; Wl[krow][nc + 1] = v.y;
    Wl[krow][nc + 2] = v.z; Wl[krow][nc + 3] = v.w;
  }
  __syncthreads();
#pragma unroll
  for (int p = 0; p < 2; ++p) {
    int gid = p * 256 + t;
    int nl = gid >> 3, kg = gid & 7;
    int xv = (nl >> 1) & 3;
    int bk = kg >> 2, s = kg & 3;
    int sp = s ^ xv;
    short8v o;
#pragma unroll
    for (int j = 0; j < 8; ++j) o[j] = f2bf(Wl[kg * 8 + j][nl]);
    *reinterpret_cast<short8v*>(
        Gp + (size_t)(n0 + nl) * K + ((k0 >> 5) + bk) * 32 + sp * 8) = o;
  }
}

__global__ __launch_bounds__(256) void prep_w(
    const float* __restrict__ W, short* __restrict__ G, int K, int Nc,
    size_t estrW, size_t estrG) {
  int e = blockIdx.z;
  prep_body(W + (size_t)e * estrW, G + (size_t)e * estrG, K, Nc);
}

// all expert weights in one launch: z = e*6 + which
__global__ __launch_bounds__(256) void prep_experts(
    const float* __restrict__ Wq, const float* __restrict__ Wk,
    const float* __restrict__ Wv, const float* __restrict__ Wo,
    const float* __restrict__ Wf1, const float* __restrict__ Wf2,
    short* __restrict__ Gw) {
  int z = blockIdx.z;
  int e = z / 6, which = z % 6;
  short* Ge = Gw + (size_t)e * GW_STRIDE;
  if (which < 4) {
    if (blockIdx.x >= 4 || blockIdx.y >= 4) return;
    const float* W =
        (which == 0 ? Wq : which == 1 ? Wk : which == 2 ? Wv : Wo) +
        (size_t)e * 65536;
    prep_body(W, Ge + (size_t)which * 65536, 256, 256);
  } else if (which == 4) {
    if (blockIdx.y >= 4) return;  // grid.x 16 all valid (Nc=1024)
    prep_body(Wf1 + (size_t)e * 262144, Ge + GW_F1, 256, 1024);
  } else {
    if (blockIdx.x >= 4) return;  // grid.y 16 all valid (K=1024)
    prep_body(Wf2 + (size_t)e * 262144, Ge + GW_F2, 1024, 256);
  }
}

// ---------------- embedding + LN -> bf16 (wave per row) --------------------
__global__ __launch_bounds__(256) void embed_ln_w(
    const float* __restrict__ h_t, const float* __restrict__ e_task,
    const float* __restrict__ e_layout, const float* __restrict__ tok,
    const float* __restrict__ pos_b, const float* __restrict__ typ_b,
    const float* __restrict__ g_b, const float* __restrict__ bb_b,
    short* __restrict__ out_b, const float* __restrict__ comb) {
  int e = blockIdx.y;
  int t = threadIdx.x, lane = t & 63, w = t >> 6;
  int row = blockIdx.x * 4 + w;
  int b = row >> 7, s = row & 127;
  if (comb[b * E + e] == 0.f) return;
  const float* pos_e = pos_b + (size_t)e * MAXPOS * D;
  const float* typ_e = typ_b + (size_t)e * D;
  const float* g = g_b + (size_t)e * D;
  const float* bb = bb_b + (size_t)e * D;
  short* outp = out_b + (size_t)e * BSD;
  int d0 = lane * 4;
  const float* src = (s >= 3) ? tok + ((size_t)(b * N + s - 3)) * D
                   : (s == 0) ? h_t + (size_t)b * D
                   : (s == 1) ? e_task + (size_t)b * D
                              : e_layout + (size_t)b * D;
  float4 x = *reinterpret_cast<const float4*>(src + d0);
  float4 pe = *reinterpret_cast<const float4*>(pos_e + (size_t)s * D + d0);
  float4 te = *reinterpret_cast<const float4*>(typ_e + d0);
  x.x += pe.x + te.x; x.y += pe.y + te.y;
  x.z += pe.z + te.z; x.w += pe.w + te.w;
  float mean = wave_sum64(x.x + x.y + x.z + x.w) * (1.f / D);
  float4 xm = {x.x - mean, x.y - mean, x.z - mean, x.w - mean};
  float vv = wave_sum64(xm.x * xm.x + xm.y * xm.y + xm.z * xm.z + xm.w * xm.w);
  float rs = rsqrtf(vv * (1.f / D) + EPS);
  float4 g4 = *reinterpret_cast<const float4*>(g + d0);
  float4 b4 = *reinterpret_cast<const float4*>(bb + d0);
  short4 o;
  o.x = f2bf(xm.x * rs * g4.x + b4.x);
  o.y = f2bf(xm.y * rs * g4.y + b4.y);
  o.z = f2bf(xm.z * rs * g4.z + b4.z);
  o.w = f2bf(xm.w * rs * g4.w + b4.w);
  *reinterpret_cast<short4*>(outp + (size_t)row * D + d0) = o;
}

// ---------------- add + LN (bf16 in/out, wave per row) ---------------------
__global__ __launch_bounds__(256) void add_ln_w(
    const short* __restrict__ A_b, const short* __restrict__ R_b,
    const float* __restrict__ g_b, const float* __restrict__ bb_b,
    short* __restrict__ out_b, const float* __restrict__ comb) {
  int e = blockIdx.y;
  int t = threadIdx.x, lane = t & 63, w = t >> 6;
  int row = blockIdx.x * 4 + w;
  int b = row >> 7;
  if (comb[b * E + e] == 0.f) return;
  const short* A = A_b + (size_t)e * BSD + (size_t)row * D;
  const short* R = R_b + (size_t)e * BSD + (size_t)row * D;
  const float* g = g_b + (size_t)e * D;
  const float* bb = bb_b + (size_t)e * D;
  short* outp = out_b + (size_t)e * BSD;
  int d0 = lane * 4;
  short4 a4 = *reinterpret_cast<const short4*>(A + d0);
  short4 r4 = *reinterpret_cast<const short4*>(R + d0);
  float4 x = {bf2f(a4.x) + bf2f(r4.x), bf2f(a4.y) + bf2f(r4.y),
              bf2f(a4.z) + bf2f(r4.z), bf2f(a4.w) + bf2f(r4.w)};
  float mean = wave_sum64(x.x + x.y + x.z + x.w) * (1.f / D);
  float4 xm = {x.x - mean, x.y - mean, x.z - mean, x.w - mean};
  float vv = wave_sum64(xm.x * xm.x + xm.y * xm.y + xm.z * xm.z + xm.w * xm.w);
  float rs = rsqrtf(vv * (1.f / D) + EPS);
  float4 g4 = *reinterpret_cast<const float4*>(g + d0);
  float4 b4 = *reinterpret_cast<const float4*>(bb + d0);
  short4 o;
  o.x = f2bf(xm.x * rs * g4.x + b4.x);
  o.y = f2bf(xm.y * rs * g4.y + b4.y);
  o.z = f2bf(xm.z * rs * g4.z + b4.z);
  o.w = f2bf(xm.w * rs * g4.w + b4.w);
  *reinterpret_cast<short4*>(outp + (size_t)row * D + d0) = o;
}

// ---------------- ln2 + gated combine fused ----------------
template <int BF16>
__global__ __launch_bounds__(256) void ln2_combine(
    const short* __restrict__ A_b, const short* __restrict__ R_b,
    const float* __restrict__ g_b, const float* __restrict__ bb_b,
    const float* __restrict__ comb, short* __restrict__ zs,
    float* __restrict__ zf) {
  int t = threadIdx.x, lane = t & 63, w = t >> 6;
  int row = blockIdx.x * 4 + w;
  int b = row >> 7;
  int d0 = lane * 4;
  float4 z4 = {0.f, 0.f, 0.f, 0.f};
  for (int e = 0; e < E; ++e) {
    float c = comb[b * E + e];
    if (c == 0.f) continue;  // wave-uniform branch
    const short* A = A_b + (size_t)e * BSD + (size_t)row * D;
    const short* R = R_b + (size_t)e * BSD + (size_t)row * D;
    short4 a4 = *reinterpret_cast<const short4*>(A + d0);
    short4 r4 = *reinterpret_cast<const short4*>(R + d0);
    float4 x = {bf2f(a4.x) + bf2f(r4.x), bf2f(a4.y) + bf2f(r4.y),
                bf2f(a4.z) + bf2f(r4.z), bf2f(a4.w) + bf2f(r4.w)};
    float mean = wave_sum64(x.x + x.y + x.z + x.w) * (1.f / D);
    float4 xm = {x.x - mean, x.y - mean, x.z - mean, x.w - mean};
    float vv =
        wave_sum64(xm.x * xm.x + xm.y * xm.y + xm.z * xm.z + xm.w * xm.w);
    float rs = rsqrtf(vv * (1.f / D) + EPS);
    float4 g4 = *reinterpret_cast<const float4*>(g_b + (size_t)e * D + d0);
    float4 b4 = *reinterpret_cast<const float4*>(bb_b + (size_t)e * D + d0);
    z4.x += c * (xm.x * rs * g4.x + b4.x);
    z4.y += c * (xm.y * rs * g4.y + b4.y);
    z4.z += c * (xm.z * rs * g4.z + b4.z);
    z4.w += c * (xm.w * rs * g4.w + b4.w);
  }
  if (BF16) {
    int col = d0;
    int xv = (row >> 1) & 3;
    int colp = (col & ~24) | ((((col >> 3) & 3) ^ xv) << 3);
    short4 o;
    o.x = f2bf(z4.x); o.y = f2bf(z4.y); o.z = f2bf(z4.z); o.w = f2bf(z4.w);
    *reinterpret_cast<short4*>(zs + (size_t)row * 256 + colp) = o;
  } else {
    *reinterpret_cast<float4*>(zf + (size_t)row * D + d0) = z4;
  }
}

// ---------------- attention: single-pass (no max), thread per query row ----
// exp without max-subtraction: softmax is shift-invariant and |s|<~3 here.
__global__ __launch_bounds__(128) void attn2_kernel(
    const short* __restrict__ Qb, const short* __restrict__ Kb,
    const short* __restrict__ Vb, short* __restrict__ Cb,
    const float* __restrict__ comb) {
  int e = blockIdx.y;
  int bh = blockIdx.x;
  int b = bh >> 3, h = bh & 7;
  if (comb[b * E + e] == 0.f) return;
  const short* Q = Qb + (size_t)e * BSD;
  const short* K = Kb + (size_t)e * BSD;
  const short* Vv = Vb + (size_t)e * BSD;
  short* C = Cb + (size_t)e * BSD;
  __shared__ float Ks[S][36];
  __shared__ float Vs[S][36];
  int t = threadIdx.x;
  const short* kbp = K + ((size_t)(b * S + t)) * D + h * HD;
  const short* vbp = Vv + ((size_t)(b * S + t)) * D + h * HD;
#pragma unroll
  for (int j = 0; j < 4; ++j) {
    short8v k8 = *reinterpret_cast<const short8v*>(kbp + j * 8);
    short8v v8 = *reinterpret_cast<const short8v*>(vbp + j * 8);
#pragma unroll
    for (int c = 0; c < 8; ++c) {
      Ks[t][j * 8 + c] = bf2f(k8[c]);
      Vs[t][j * 8 + c] = bf2f(v8[c]);
    }
  }
  float4 qv[8];
  const short* qp = Q + ((size_t)(b * S + t)) * D + h * HD;
#pragma unroll
  for (int j = 0; j < 4; ++j) {
    short8v q8 = *reinterpret_cast<const short8v*>(qp + j * 8);
    qv[j * 2] = (float4){bf2f(q8[0]), bf2f(q8[1]), bf2f(q8[2]), bf2f(q8[3])};
    qv[j * 2 + 1] =
        (float4){bf2f(q8[4]), bf2f(q8[5]), bf2f(q8[6]), bf2f(q8[7])};
  }
  __syncthreads();
  const float scale = 0.17677669529663687f;  // 1/sqrt(32)
  float se = 0.f;
  float4 cx[8];
#pragma unroll
  for (int j = 0; j < 8; ++j) cx[j] = (float4){0.f, 0.f, 0.f, 0.f};
  for (int k = 0; k < S; ++k) {
    float s = 0.f;
#pragma unroll
    for (int j = 0; j < 8; ++j) {
      float4 k4 = *reinterpret_cast<const float4*>(&Ks[k][j * 4]);
      s += qv[j].x * k4.x + qv[j].y * k4.y + qv[j].z * k4.z + qv[j].w * k4.w;
    }
    float p = expf(s * scale);
    se += p;
#pragma unroll
    for (int j = 0; j < 8; ++j) {
      float4 v4 = *reinterpret_cast<const float4*>(&Vs[k][j * 4]);
      cx[j].x += p * v4.x; cx[j].y += p * v4.y;
      cx[j].z += p * v4.z; cx[j].w += p * v4.w;
    }
  }
  float inv = 1.f / se;
  short* cp = C + ((size_t)(b * S + t)) * D + h * HD;
#pragma unroll
  for (int j = 0; j < 8; ++j) {
    short4 o;
    o.x = f2bf(cx[j].x * inv); o.y = f2bf(cx[j].y * inv);
    o.z = f2bf(cx[j].z * inv); o.w = f2bf(cx[j].w * inv);
    *reinterpret_cast<short4*>(cp + j * 4) = o;
  }
}

// ---------------- GEMM v2 body (BM=128): A LDS stage, B global_load_lds ----
template <int ACT, int K, int Nc, int ABF16, int OBF16>
__device__ __forceinline__ void gemm2_body(
    const char* __restrict__ Ag, const short* __restrict__ Gg,
    const float* __restrict__ bias, char* __restrict__ outp, int row0,
    int col0) {
  __shared__ short Al[128 * 40];
  __shared__ short Bl[128 * 32];
  const int t = threadIdx.x;
  const int lane = t & 63;
  const int w = t >> 6;
  const int wr = w >> 1, wc = w & 1;
  const int lrow = lane & 15;
  const int g = lane >> 4;
  const int lkoff = g * 8;                         // A frag k-half
  const int koff = (g ^ ((lrow >> 1) & 3)) << 3;   // B frag (swizzled)
  const char* Gb = (const char*)Gg;
  char* Bb = (char*)Bl;
  const int srow = t >> 2, sgrp = t & 3;
  const int woff = w * 1024;

  f32x4 acc[4][4];
#pragma unroll
  for (int m = 0; m < 4; ++m)
#pragma unroll
    for (int n = 0; n < 4; ++n) acc[m][n] = (f32x4){0.f, 0.f, 0.f, 0.f};

  for (int k0 = 0; k0 < K; k0 += 32) {
#pragma unroll
    for (int i = 0; i < 2; ++i) {
      int row = i * 64 + srow;
      gload16(Gb + (size_t)(col0 + row) * (K * 2) + (k0 >> 5) * 64 + sgrp * 16,
              Bb + i * 4096 + woff);
    }
    if (ABF16) {
      int row = t >> 1, c0 = (t & 1) * 2;
#pragma unroll
      for (int c = 0; c < 2; ++c) {
        short8v v = *reinterpret_cast<const short8v*>(
            (const short*)Ag + (size_t)(row0 + row) * K + k0 + (c0 + c) * 8);
        *reinterpret_cast<short8v*>(&Al[row * 40 + (c0 + c) * 8]) = v;
      }
    } else {
#pragma unroll
      for (int j = 0; j < 4; ++j) {
        int id = t + 256 * j;
        int row = id >> 3, s4 = id & 7;
        float4 a4 = *reinterpret_cast<const float4*>(
            (const float*)Ag + (size_t)(row0 + row) * K + k0 + s4 * 4);
        short4 p;
        p.x = f2bf(a4.x); p.y = f2bf(a4.y); p.z = f2bf(a4.z); p.w = f2bf(a4.w);
        *reinterpret_cast<short4*>(&Al[row * 40 + s4 * 4]) = p;
      }
    }
    __syncthreads();
    short8v af[4], bfv[4];
#pragma unroll
    for (int m = 0; m < 4; ++m)
      af[m] = *reinterpret_cast<const short8v*>(
          &Al[(wr * 64 + m * 16 + lrow) * 40 + lkoff]);
#pragma unroll
    for (int n = 0; n < 4; ++n)
      bfv[n] = *reinterpret_cast<const short8v*>(
          &Bl[(wc * 64 + n * 16 + lrow) * 32 + koff]);
#pragma unroll
    for (int m = 0; m < 4; ++m)
#pragma unroll
      for (int n = 0; n < 4; ++n)
        acc[m][n] = __builtin_amdgcn_mfma_f32_16x16x32_bf16(
            af[m], bfv[n], acc[m][n], 0, 0, 0);
    __syncthreads();
  }
#pragma unroll
  for (int n = 0; n < 4; ++n) {
    int col = col0 + wc * 64 + n * 16 + lrow;
    float bc = bias[col];
#pragma unroll
    for (int m = 0; m < 4; ++m) {
      int rbase = row0 + wr * 64 + m * 16 + g * 4;
      f32x4 v = acc[m][n];
#pragma unroll
      for (int r = 0; r < 4; ++r) {
        float o = v[r] + bc;
        if (ACT == 1) o = gelu_exact(o);
        if (OBF16)
          ((short*)outp)[(size_t)(rbase + r) * Nc + col] = f2bf(o);
        else
          ((float*)outp)[(size_t)(rbase + r) * Nc + col] = o;
      }
    }
  }
}

// ---------------- GEMM v2 body (BM=64) ----------------
template <int ACT, int K, int Nc, int ABF16, int OBF16>
__device__ __forceinline__ void gemm2_body64(
    const char* __restrict__ Ag, const short* __restrict__ Gg,
    const float* __restrict__ bias, char* __restrict__ outp, int row0,
    int col0) {
  __shared__ short Al[64 * 40];
  __shared__ short Bl[128 * 32];
  const int t = threadIdx.x;
  const int lane = t & 63;
  const int w = t >> 6;          // 0..3 -> 32-col group
  const int lrow = lane & 15;
  const int g = lane >> 4;
  const int lkoff = g * 8;
  const int koff = (g ^ ((lrow >> 1) & 3)) << 3;
  const char* Gb = (const char*)Gg;
  char* Bb = (char*)Bl;
  const int srow = t >> 2, sgrp = t & 3;
  const int woff = w * 1024;

  f32x4 acc[4][2];
#pragma unroll
  for (int m = 0; m < 4; ++m)
#pragma unroll
    for (int n = 0; n < 2; ++n) acc[m][n] = (f32x4){0.f, 0.f, 0.f, 0.f};

  for (int k0 = 0; k0 < K; k0 += 32) {
#pragma unroll
    for (int i = 0; i < 2; ++i) {
      int row = i * 64 + srow;
      gload16(Gb + (size_t)(col0 + row) * (K * 2) + (k0 >> 5) * 64 + sgrp * 16,
              Bb + i * 4096 + woff);
    }
    if (ABF16) {
      int row = t >> 2, seg = t & 3;
      short8v v = *reinterpret_cast<const short8v*>(
          (const short*)Ag + (size_t)(row0 + row) * K + k0 + seg * 8);
      *reinterpret_cast<short8v*>(&Al[row * 40 + seg * 8]) = v;
    } else {
#pragma unroll
      for (int j = 0; j < 2; ++j) {
        int id = t + 256 * j;
        int row = id >> 3, s4 = id & 7;
        float4 a4 = *reinterpret_cast<const float4*>(
            (const float*)Ag + (size_t)(row0 + row) * K + k0 + s4 * 4);
        short4 p;
        p.x = f2bf(a4.x); p.y = f2bf(a4.y); p.z = f2bf(a4.z); p.w = f2bf(a4.w);
        *reinterpret_cast<short4*>(&Al[row * 40 + s4 * 4]) = p;
      }
    }
    __syncthreads();
    short8v af[4], bfv[2];
#pragma unroll
    for (int m = 0; m < 4; ++m)
      af[m] = *reinterpret_cast<const short8v*>(
          &Al[(m * 16 + lrow) * 40 + lkoff]);
#pragma unroll
    for (int n = 0; n < 2; ++n)
      bfv[n] = *reinterpret_cast<const short8v*>(
          &Bl[(w * 32 + n * 16 + lrow) * 32 + koff]);
#pragma unroll
    for (int m = 0; m < 4; ++m)
#pragma unroll
      for (int n = 0; n < 2; ++n)
        acc[m][n] = __builtin_amdgcn_mfma_f32_16x16x32_bf16(
            af[m], bfv[n], acc[m][n], 0, 0, 0);
    __syncthreads();
  }
#pragma unroll
  for (int n = 0; n < 2; ++n) {
    int col = col0 + w * 32 + n * 16 + lrow;
    float bc = bias[col];
#pragma unroll
    for (int m = 0; m < 4; ++m) {
      int rbase = row0 + m * 16 + g * 4;
      f32x4 v = acc[m][n];
#pragma unroll
      for (int r = 0; r < 4; ++r) {
        float o = v[r] + bc;
        if (ACT == 1) o = gelu_exact(o);
        if (OBF16)
          ((short*)outp)[(size_t)(rbase + r) * Nc + col] = f2bf(o);
        else
          ((float*)outp)[(size_t)(rbase + r) * Nc + col] = o;
      }
    }
  }
}

// generic per-expert GEMMs
template <int ACT, int K, int Nc, int ABF16, int OBF16>
__global__ __launch_bounds__(256) void gemm2_e(
    const char* __restrict__ Ab, const short* __restrict__ Gbase,
    const float* __restrict__ biasb, char* __restrict__ outb,
    const float* __restrict__ comb, size_t aStrB, size_t oStrB, int bStr) {
  int e = blockIdx.z;
  int row0 = blockIdx.y * 128;
  int col0 = blockIdx.x * 128;
  if (comb[(row0 >> 7) * E + e] == 0.f) return;
  gemm2_body<ACT, K, Nc, ABF16, OBF16>(
      Ab + (size_t)e * aStrB, Gbase + (size_t)e * GW_STRIDE,
      biasb + (size_t)e * bStr, outb + (size_t)e * oStrB, row0, col0);
}

template <int ACT, int K, int Nc, int ABF16, int OBF16>
__global__ __launch_bounds__(256) void gemm2b64_e(
    const char* __restrict__ Ab, const short* __restrict__ Gbase,
    const float* __restrict__ biasb, char* __restrict__ outb,
    const float* __restrict__ comb, size_t aStrB, size_t oStrB, int bStr) {
  int e = blockIdx.z;
  int row0 = blockIdx.y * 64;
  int col0 = blockIdx.x * 128;
  if (comb[(row0 >> 7) * E + e] == 0.f) return;
  gemm2_body64<ACT, K, Nc, ABF16, OBF16>(
      Ab + (size_t)e * aStrB, Gbase + (size_t)e * GW_STRIDE,
      biasb + (size_t)e * bStr, outb + (size_t)e * oStrB, row0, col0);
}

// fused QKV v2 (bf16 A, bf16 out)
__global__ __launch_bounds__(256) void qkv2_e(
    const short* __restrict__ h0b, const short* __restrict__ Gw,
    const float* __restrict__ bqb, const float* __restrict__ bkb,
    const float* __restrict__ bvb, short* __restrict__ qb,
    short* __restrict__ kb, short* __restrict__ vb,
    const float* __restrict__ comb) {
  int e = blockIdx.z;
  int which = blockIdx.x >> 1;
  int col0 = (blockIdx.x & 1) * 128;
  int row0 = blockIdx.y * 128;
  if (comb[(row0 >> 7) * E + e] == 0.f) return;
  const short* G = Gw + (size_t)e * GW_STRIDE + (size_t)which * 65536;
  const float* bias =
      (which == 0 ? bqb : which == 1 ? bkb : bvb) + (size_t)e * D;
  short* outp = (which == 0 ? qb : which == 1 ? kb : vb) + (size_t)e * BSD;
  gemm2_body<0, D, D, 1, 1>((const char*)(h0b + (size_t)e * BSD), G, bias,
                            (char*)outp, row0, col0);
}

// ---------------- fallback fp32-W GEMM (head fallback only) ----------------
template <int ACT, int K, int Nc>
__device__ __forceinline__ void gemm_body(
    const float* __restrict__ Ag, const float* __restrict__ Wg,
    const float* __restrict__ bias, float* __restrict__ outp, int row0,
    int col0) {
  __shared__ short Al[128 * 40];
  __shared__ short Bl[128 * 40];
  const int t = threadIdx.x;
  const int lane = t & 63;
  const int w = t >> 6;
  const int wr = w >> 1, wc = w & 1;
  const int lrow = lane & 15;
  const int lkoff = (lane >> 4) * 8;
  f32x4 acc[4][4];
#pragma unroll
  for (int m = 0; m < 4; ++m)
#pragma unroll
    for (int n = 0; n < 4; ++n) acc[m][n] = (f32x4){0.f, 0.f, 0.f, 0.f};
  const int colB = t >> 1, kh = (t & 1) * 16;
  for (int k0 = 0; k0 < K; k0 += 32) {
#pragma unroll
    for (int j = 0; j < 4; ++j) {
      int id = t + 256 * j;
      int row = id >> 3, s4 = id & 7;
      float4 a4 = *reinterpret_cast<const float4*>(
          Ag + (size_t)(row0 + row) * K + k0 + s4 * 4);
      short4 p;
      p.x = f2bf(a4.x); p.y = f2bf(a4.y); p.z = f2bf(a4.z); p.w = f2bf(a4.w);
      *reinterpret_cast<short4*>(&Al[row * 40 + s4 * 4]) = p;
    }
    {
      const float* wp = Wg + (size_t)(k0 + kh) * Nc + (col0 + colB);
      short8v v0, v1;
#pragma unroll
      for (int kk = 0; kk < 8; ++kk) v0[kk] = f2bf(wp[(size_t)kk * Nc]);
#pragma unroll
      for (int kk = 0; kk < 8; ++kk) v1[kk] = f2bf(wp[(size_t)(kk + 8) * Nc]);
      *reinterpret_cast<short8v*>(&Bl[colB * 40 + kh]) = v0;
      *reinterpret_cast<short8v*>(&Bl[colB * 40 + kh + 8]) = v1;
    }
    __syncthreads();
    short8v af[4], bfv[4];
#pragma unroll
    for (int m = 0; m < 4; ++m)
      af[m] = *reinterpret_cast<const short8v*>(
          &Al[(wr * 64 + m * 16 + lrow) * 40 + lkoff]);
#pragma unroll
    for (int n = 0; n < 4; ++n)
      bfv[n] = *reinterpret_cast<const short8v*>(
          &Bl[(wc * 64 + n * 16 + lrow) * 40 + lkoff]);
#pragma unroll
    for (int m = 0; m < 4; ++m)
#pragma unroll
      for (int n = 0; n < 4; ++n)
        acc[m][n] = __builtin_amdgcn_mfma_f32_16x16x32_bf16(
            af[m], bfv[n], acc[m][n], 0, 0, 0);
    __syncthreads();
  }
#pragma unroll
  for (int n = 0; n < 4; ++n) {
    int col = col0 + wc * 64 + n * 16 + lrow;
    float bc = bias[col];
#pragma unroll
    for (int m = 0; m < 4; ++m) {
      int rbase = row0 + wr * 64 + m * 16 + (lane >> 4) * 4;
      f32x4 v = acc[m][n];
#pragma unroll
      for (int r = 0; r < 4; ++r) {
        float o = v[r] + bc;
        if (ACT == 1) o = gelu_exact(o);
        outp[(size_t)(rbase + r) * Nc + col] = o;
      }
    }
  }
}

__global__ __launch_bounds__(256) void head_gemm(
    const float* __restrict__ Ag, const float* __restrict__ Wg,
    const float* __restrict__ bias, float* __restrict__ outp) {
  int row0 = blockIdx.x * 128;
  int col0 = blockIdx.y * 128;
  gemm_body<0, D, V>(Ag, Wg, bias, outp, row0, col0);
}

// ---------------- head GEMM v2: async bf16 + XCD-contiguous remap ----------
// ONLY change vs r11: bijective remap so each XCD's L2 holds its own ~31
// G col-stripes (2 MB < 4 MB L2) instead of all 8 L2s re-fetching every
// stripe (r4 counters: FETCH 149 MB = 9x G size).
__global__ __launch_bounds__(256) void head_gemm2(
    const short* __restrict__ zs, const short* __restrict__ G,
    const float* __restrict__ bias, float* __restrict__ outp) {
  __shared__ short Al[128 * 32];
  __shared__ short Bl[128 * 32];
  int flat = blockIdx.x + (blockIdx.y << 5);      // grid (32, 250) -> 8000
  int flat2 = (flat & 7) * 1000 + (flat >> 3);    // bijective: xcd-chunked
  const int row0 = (flat2 & 31) << 7;             // rows fastest in chunk
  const int col0 = (flat2 >> 5) << 7;
  const int t = threadIdx.x;
  const int lane = t & 63, w = t >> 6;
  const int wr = w >> 1, wc = w & 1;
  const int lrow = lane & 15;
  const int g = lane >> 4;
  const int koff = (g ^ ((lrow >> 1) & 3)) << 3;
  const int srow = t >> 2, sgrp = t & 3;
  const char* zsb = (const char*)zs;
  const char* Gb = (const char*)G;
  char* Ab = (char*)Al;
  char* Bb = (char*)Bl;
  const int woff = w * 1024;

  f32x4 acc[4][4];
#pragma unroll
  for (int m = 0; m < 4; ++m)
#pragma unroll
    for (int n = 0; n < 4; ++n) acc[m][n] = (f32x4){0.f, 0.f, 0.f, 0.f};

  for (int kb = 0; kb < 8; ++kb) {
#pragma unroll
    for (int i = 0; i < 2; ++i) {
      int row = i * 64 + srow;
      gload16(zsb + (size_t)(row0 + row) * 512 + kb * 64 + sgrp * 16,
              Ab + i * 4096 + woff);
      gload16(Gb + (size_t)(col0 + row) * 512 + kb * 64 + sgrp * 16,
              Bb + i * 4096 + woff);
    }
    __syncthreads();
    short8v af[4], bfv[4];
#pragma unroll
    for (int m = 0; m < 4; ++m)
      af[m] = *reinterpret_cast<const short8v*>(
          &Al[(wr * 64 + m * 16 + lrow) * 32 + koff]);
#pragma unroll
    for (int n = 0; n < 4; ++n)
      bfv[n] = *reinterpret_cast<const short8v*>(
          &Bl[(wc * 64 + n * 16 + lrow) * 32 + koff]);
#pragma unroll
    for (int m = 0; m < 4; ++m)
#pragma unroll
      for (int n = 0; n < 4; ++n)
        acc[m][n] = __builtin_amdgcn_mfma_f32_16x16x32_bf16(
            af[m], bfv[n], acc[m][n], 0, 0, 0);
    __syncthreads();
  }
#pragma unroll
  for (int n = 0; n < 4; ++n) {
    int col = col0 + wc * 64 + n * 16 + lrow;
    float bc = bias[col];
#pragma unroll
    for (int m = 0; m < 4; ++m) {
      int rbase = row0 + wr * 64 + m * 16 + g * 4;
      f32x4 v = acc[m][n];
#pragma unroll
      for (int r = 0; r < 4; ++r)
        outp[(size_t)(rbase + r) * V + col] = v[r] + bc;
    }
  }
}

// fallback combine reading bf16 h (only used when ws too small)
__global__ __launch_bounds__(256) void combine_f32(
    const short* __restrict__ hb, const float* __restrict__ comb,
    float* __restrict__ zf) {
  size_t i = ((size_t)blockIdx.x * 256 + threadIdx.x) * 4;
  int b = (int)(i >> 15);
  float4 acc = {0.f, 0.f, 0.f, 0.f};
#pragma unroll
  for (int e2 = 0; e2 < E; ++e2) {
    float c = comb[b * E + e2];
    if (c != 0.f) {
      short4 v = *reinterpret_cast<const short4*>(hb + (size_t)e2 * BSD + i);
      acc.x += c * bf2f(v.x); acc.y += c * bf2f(v.y);
      acc.z += c * bf2f(v.z); acc.w += c * bf2f(v.w);
    }
  }
  *reinterpret_cast<float4*>(zf + i) = acc;
}

}  // namespace

extern "C" void kernel_launch(void* const* d_in, const int* in_sizes, int n_in,
                              void* d_out, int out_size, void* d_ws,
                              size_t ws_size, hipStream_t stream) {
  const float* h_t = (const float*)d_in[0];
  const float* e_task = (const float*)d_in[1];
  const float* e_layout = (const float*)d_in[2];
  const float* tok = (const float*)d_in[3];
  const float* rW1 = (const float*)d_in[4];
  const float* rb1 = (const float*)d_in[5];
  const float* rW2 = (const float*)d_in[6];
  const float* rb2 = (const float*)d_in[7];
  const float* hW = (const float*)d_in[8];
  const float* hb = (const float*)d_in[9];
  const float* pos = (const float*)d_in[10];
  const float* typ = (const float*)d_in[11];
  const float* g0 = (const float*)d_in[12];
  const float* b0 = (const float*)d_in[13];
  const float* Wq = (const float*)d_in[14];
  const float* bq = (const float*)d_in[15];
  const float* Wk = (const float*)d_in[16];
  const float* bk = (const float*)d_in[17];
  const float* Wv = (const float*)d_in[18];
  const float* bv = (const float*)d_in[19];
  const float* Wo = (const float*)d_in[20];
  const float* bo = (const float*)d_in[21];
  const float* g1 = (const float*)d_in[22];
  const float* b1 = (const float*)d_in[23];
  const float* Wf1 = (const float*)d_in[24];
  const float* bf1 = (const float*)d_in[25];
  const float* Wf2 = (const float*)d_in[26];
  const float* bf2 = (const float*)d_in[27];
  const float* g2 = (const float*)d_in[28];
  const float* b2 = (const float*)d_in[29];
  const float* headW = (const float*)d_in[30];
  const float* headb = (const float*)d_in[31];
  const int* topk = (const int*)d_in[32];

  float* out = (float*)d_out;
  float* gp_out = out + (size_t)B * S * V;  // gate_probs tail of d_out

  // bf16 scratch in the logits region of d_out (~58 MB < 524 MB; all dead
  // before head GEMM overwrites it).
  short* h0s = (short*)out;               // [E][B*S, D]
  short* qs = h0s + (size_t)E * BSD;
  short* ks = qs + (size_t)E * BSD;
  short* vs = ks + (size_t)E * BSD;
  short* ctxs = vs + (size_t)E * BSD;
  short* fbh = ctxs + (size_t)E * BSD;    // [E][B*S, FF]
  short* Gw = fbh + (size_t)E * BSF;      // 7.9 MB expert weights

  // d_ws: G_head bf16 | comb | gp | zs bf16  (18.5 MB, proven)
  float* wsf = (float*)d_ws;
  short* Ghead = (short*)d_ws;              // 16,384,000 B
  float* comb = wsf + 4096000;
  float* gp = comb + 256;
  short* zs = (short*)(wsf + 4096512);      // 2,097,152 B
  size_t need = (size_t)4096512 * 4 + (size_t)4096 * 256 * 2;
  bool fast_head = ws_size >= need;
  if (!fast_head) {
    comb = wsf;
    gp = comb + 256;
  }
  float* zf = gp + 256;  // fp32 z for head fallback only

  // weight pre-passes
  if (fast_head)
    prep_w<<<dim3(V / 64, 4, 1), 256, 0, stream>>>(headW, Ghead, 256, V, 0, 0);
  prep_experts<<<dim3(16, 16, E * 6), 256, 0, stream>>>(Wq, Wk, Wv, Wo, Wf1,
                                                        Wf2, Gw);

  router1_kernel<<<B, HID, 0, stream>>>(h_t, e_task, e_layout, rW1, rb1, rW2,
                                        rb2, hW, hb, gp, gp_out);
  router2_kernel<<<1, 64, 0, stream>>>(gp, topk, comb);

  dim3 gLN(B * S / 4, E);
  embed_ln_w<<<gLN, 256, 0, stream>>>(h_t, e_task, e_layout, tok, pos, typ,
                                      g0, b0, h0s, comb);
  qkv2_e<<<dim3(6, 32, E), 256, 0, stream>>>(h0s, Gw, bq, bk, bv, qs, ks, vs,
                                             comb);
  attn2_kernel<<<dim3(B * H, E), 128, 0, stream>>>(qs, ks, vs, ctxs, comb);
  gemm2b64_e<0, 256, 256, 1, 1><<<dim3(2, 64, E), 256, 0, stream>>>(
      (const char*)ctxs, Gw + GW_O, bo, (char*)qs, comb, (size_t)BSD * 2,
      (size_t)BSD * 2, 256);
  add_ln_w<<<gLN, 256, 0, stream>>>(h0s, qs, g1, b1, ks, comb);
  gemm2_e<1, 256, 1024, 1, 1><<<dim3(8, 32, E), 256, 0, stream>>>(
      (const char*)ks, Gw + GW_F1, bf1, (char*)fbh, comb, (size_t)BSD * 2,
      (size_t)BSF * 2, FF);
  gemm2b64_e<0, 1024, 256, 1, 1><<<dim3(2, 64, E), 256, 0, stream>>>(
      (const char*)fbh, Gw + GW_F2, bf2, (char*)vs, comb, (size_t)BSF * 2,
      (size_t)BSD * 2, 256);

  if (fast_head) {
    ln2_combine<1><<<B * S / 4, 256, 0, stream>>>(ks, vs, g2, b2, comb, zs,
                                                  nullptr);
    head_gemm2<<<dim3(32, V / 128), 256, 0, stream>>>(zs, Ghead, headb, out);
  } else {
    add_ln_w<<<gLN, 256, 0, stream>>>(ks, vs, g2, b2, h0s, comb);
    combine_f32<<<BSD / 1024, 256, 0, stream>>>(h0s, comb, zf);
    head_gemm<<<dim3(32, V / 128), 256, 0, stream>>>(zf, headW, headb, out);
  }
  (void)in_sizes; (void)n_in; (void)out_size;
}

// Round 13
// 375.874 us; speedup vs baseline: 1.1546x; 1.1546x over previous
//
#include <hip/hip_runtime.h>
#include <hip/hip_bf16.h>
#include <math.h>

namespace {

constexpr int B = 32, N = 125, D = 256, H = 8, HD = 32, FF = 1024,
              E = 5, V = 32000, HID = 128, S = 128, MAXPOS = 512;
constexpr int BSD = B * S * D;     // 1,048,576
constexpr int BSF = B * S * FF;    // 4,194,304
constexpr float EPS = 1e-12f;
constexpr float THRESH = 0.7f;

// per-expert G-format weight block: Gq|Gk|Gv|Go|Gf1|Gf2 (shorts)
constexpr size_t GW_Q = 0, GW_K = 65536, GW_V = 131072, GW_O = 196608,
                 GW_F1 = 262144, GW_F2 = 524288, GW_STRIDE = 786432;

typedef __attribute__((ext_vector_type(4))) float f32x4;
typedef __attribute__((ext_vector_type(8))) short short8v;

__device__ __forceinline__ short f2bf(float f) {
  __hip_bfloat16 h = __float2bfloat16(f);  // RNE
  short s;
  __builtin_memcpy(&s, &h, 2);
  return s;
}

__device__ __forceinline__ float bf2f(short s) {
  unsigned int u = ((unsigned int)(unsigned short)s) << 16;
  float f;
  __builtin_memcpy(&f, &u, 4);
  return f;
}

__device__ __forceinline__ float gelu_exact(float x) {
  return 0.5f * x * (1.f + erff(x * 0.70710678118654752f));
}

__device__ __forceinline__ float wave_sum64(float v) {
#pragma unroll
  for (int off = 32; off > 0; off >>= 1) v += __shfl_xor(v, off);
  return v;
}

// async global->LDS, 16B per lane; lds dest = wave-uniform base + lane*16
__device__ __forceinline__ void gload16(const void* g, void* l) {
  __builtin_amdgcn_global_load_lds(
      (const __attribute__((address_space(1))) unsigned int*)g,
      (__attribute__((address_space(3))) unsigned int*)l, 16, 0, 0);
}

// ---------------- router ----------------
__global__ __launch_bounds__(HID) void router1_kernel(
    const float* __restrict__ h_t, const float* __restrict__ e_task,
    const float* __restrict__ e_layout, const float* __restrict__ W1,
    const float* __restrict__ b1, const float* __restrict__ W2,
    const float* __restrict__ b2, const float* __restrict__ hintW,
    const float* __restrict__ hintb, float* __restrict__ gp_ws,
    float* __restrict__ gp_out) {
  int b = blockIdx.x;
  int t = threadIdx.x;
  float acc = b1[t];
  const float* rows[3] = {h_t + b * D, e_task + b * D, e_layout + b * D};
  for (int seg = 0; seg < 3; ++seg) {
    const float* r = rows[seg];
    const float* w = W1 + (size_t)seg * D * HID;
    for (int i = 0; i < D; ++i) acc += r[i] * w[i * HID + t];
  }
  __shared__ float hid[HID];
  __shared__ float logits[E];
  hid[t] = fmaxf(acc, 0.f);
  __syncthreads();
  if (t < E) {
    float l = b2[t] + hintb[t];
    for (int hh = 0; hh < HID; ++hh) l += hid[hh] * W2[hh * E + t];
    const float* el = e_layout + b * D;
    for (int dd = 0; dd < D; ++dd) l += el[dd] * hintW[dd * E + t];
    logits[t] = l;
  }
  __syncthreads();
  if (t == 0) {
    float mx = logits[0];
    for (int e2 = 1; e2 < E; ++e2) mx = fmaxf(mx, logits[e2]);
    float p[E];
    float se = 0.f;
    for (int e2 = 0; e2 < E; ++e2) {
      p[e2] = expf(logits[e2] - mx);
      se += p[e2];
    }
    float inv = 1.f / se;
    for (int e2 = 0; e2 < E; ++e2) {
      float pe = p[e2] * inv;
      gp_ws[b * E + e2] = pe;
      gp_out[b * E + e2] = pe;
    }
  }
}

__global__ __launch_bounds__(64) void router2_kernel(
    const float* __restrict__ gp, const int* __restrict__ topk_ptr,
    float* __restrict__ comb) {
  __shared__ int allk1;
  int t = threadIdx.x;
  if (t == 0) allk1 = 1;
  __syncthreads();
  float p[E];
  if (t < B) {
    float mx = 0.f;
    for (int e2 = 0; e2 < E; ++e2) {
      p[e2] = gp[t * E + e2];
      mx = fmaxf(mx, p[e2]);
    }
    if (!(mx > THRESH)) allk1 = 0;  // benign race: all writers store 0
  }
  __syncthreads();
  int k1 = allk1;
  if (t < B) {
    for (int e2 = 0; e2 < E; ++e2) comb[t * E + e2] = 0.f;
    int tk = *topk_ptr;
    if (tk > E) tk = E;
    float q[E];
    for (int e2 = 0; e2 < E; ++e2) q[e2] = p[e2];
    for (int kk = 0; kk < tk; ++kk) {
      int bi = 0;
      float bv = q[0];
      for (int e2 = 1; e2 < E; ++e2)
        if (q[e2] > bv) { bv = q[e2]; bi = e2; }
      float w = (kk == 0) ? bv : (k1 ? 0.f : bv);
      comb[t * E + bi] += w;
      q[bi] = -1.f;
    }
  }
}

// ---------------- weight pre-pass: W[K][Nc] f32 -> G[Nc][K] bf16 swizzled --
__device__ __forceinline__ void prep_body(const float* __restrict__ Wp,
                                          short* __restrict__ Gp, int K,
                                          int Nc) {
  __shared__ float Wl[64][65];
  int t = threadIdx.x;
  int n0 = blockIdx.x * 64, k0 = blockIdx.y * 64;
#pragma unroll
  for (int p = 0; p < 4; ++p) {
    int krow = p * 16 + (t >> 4);
    int nc = (t & 15) * 4;
    float4 v = *reinterpret_cast<const float4*>(
        Wp + (size_t)(k0 + krow) * Nc + n0 + nc);
    Wl[krow][nc] = v.x; Wl[krow][nc + 1] = v.y;
    Wl[krow][nc + 2] = v.z; Wl[krow][nc + 3] = v.w;
  }
  __syncthreads();
#pragma unroll
  for (int p = 0; p < 2; ++p) {
    int gid = p * 256 + t;
    int nl = gid >> 3, kg = gid & 7;
    int xv = (nl >> 1) & 3;
    int bk = kg >> 2, s = kg & 3;
    int sp = s ^ xv;
    short8v o;
#pragma unroll
    for (int j = 0; j < 8; ++j) o[j] = f2bf(Wl[kg * 8 + j][nl]);
    *reinterpret_cast<short8v*>(
        Gp + (size_t)(n0 + nl) * K + ((k0 >> 5) + bk) * 32 + sp * 8) = o;
  }
}

__global__ __launch_bounds__(256) void prep_w(
    const float* __restrict__ W, short* __restrict__ G, int K, int Nc,
    size_t estrW, size_t estrG) {
  int e = blockIdx.z;
  prep_body(W + (size_t)e * estrW, G + (size_t)e * estrG, K, Nc);
}

// all expert weights in one launch: z = e*6 + which
__global__ __launch_bounds__(256) void prep_experts(
    const float* __restrict__ Wq, const float* __restrict__ Wk,
    const float* __restrict__ Wv, const float* __restrict__ Wo,
    const float* __restrict__ Wf1, const float* __restrict__ Wf2,
    short* __restrict__ Gw) {
  int z = blockIdx.z;
  int e = z / 6, which = z % 6;
  short* Ge = Gw + (size_t)e * GW_STRIDE;
  if (which < 4) {
    if (blockIdx.x >= 4 || blockIdx.y >= 4) return;
    const float* W =
        (which == 0 ? Wq : which == 1 ? Wk : which == 2 ? Wv : Wo) +
        (size_t)e * 65536;
    prep_body(W, Ge + (size_t)which * 65536, 256, 256);
  } else if (which == 4) {
    if (blockIdx.y >= 4) return;  // grid.x 16 all valid (Nc=1024)
    prep_body(Wf1 + (size_t)e * 262144, Ge + GW_F1, 256, 1024);
  } else {
    if (blockIdx.x >= 4) return;  // grid.y 16 all valid (K=1024)
    prep_body(Wf2 + (size_t)e * 262144, Ge + GW_F2, 1024, 256);
  }
}

// ---------------- embedding + LN -> bf16 (wave per row) --------------------
__global__ __launch_bounds__(256) void embed_ln_w(
    const float* __restrict__ h_t, const float* __restrict__ e_task,
    const float* __restrict__ e_layout, const float* __restrict__ tok,
    const float* __restrict__ pos_b, const float* __restrict__ typ_b,
    const float* __restrict__ g_b, const float* __restrict__ bb_b,
    short* __restrict__ out_b, const float* __restrict__ comb) {
  int e = blockIdx.y;
  int t = threadIdx.x, lane = t & 63, w = t >> 6;
  int row = blockIdx.x * 4 + w;
  int b = row >> 7, s = row & 127;
  if (comb[b * E + e] == 0.f) return;
  const float* pos_e = pos_b + (size_t)e * MAXPOS * D;
  const float* typ_e = typ_b + (size_t)e * D;
  const float* g = g_b + (size_t)e * D;
  const float* bb = bb_b + (size_t)e * D;
  short* outp = out_b + (size_t)e * BSD;
  int d0 = lane * 4;
  const float* src = (s >= 3) ? tok + ((size_t)(b * N + s - 3)) * D
                   : (s == 0) ? h_t + (size_t)b * D
                   : (s == 1) ? e_task + (size_t)b * D
                              : e_layout + (size_t)b * D;
  float4 x = *reinterpret_cast<const float4*>(src + d0);
  float4 pe = *reinterpret_cast<const float4*>(pos_e + (size_t)s * D + d0);
  float4 te = *reinterpret_cast<const float4*>(typ_e + d0);
  x.x += pe.x + te.x; x.y += pe.y + te.y;
  x.z += pe.z + te.z; x.w += pe.w + te.w;
  float mean = wave_sum64(x.x + x.y + x.z + x.w) * (1.f / D);
  float4 xm = {x.x - mean, x.y - mean, x.z - mean, x.w - mean};
  float vv = wave_sum64(xm.x * xm.x + xm.y * xm.y + xm.z * xm.z + xm.w * xm.w);
  float rs = rsqrtf(vv * (1.f / D) + EPS);
  float4 g4 = *reinterpret_cast<const float4*>(g + d0);
  float4 b4 = *reinterpret_cast<const float4*>(bb + d0);
  short4 o;
  o.x = f2bf(xm.x * rs * g4.x + b4.x);
  o.y = f2bf(xm.y * rs * g4.y + b4.y);
  o.z = f2bf(xm.z * rs * g4.z + b4.z);
  o.w = f2bf(xm.w * rs * g4.w + b4.w);
  *reinterpret_cast<short4*>(outp + (size_t)row * D + d0) = o;
}

// ---------------- add + LN (bf16 in/out, wave per row) ---------------------
__global__ __launch_bounds__(256) void add_ln_w(
    const short* __restrict__ A_b, const short* __restrict__ R_b,
    const float* __restrict__ g_b, const float* __restrict__ bb_b,
    short* __restrict__ out_b, const float* __restrict__ comb) {
  int e = blockIdx.y;
  int t = threadIdx.x, lane = t & 63, w = t >> 6;
  int row = blockIdx.x * 4 + w;
  int b = row >> 7;
  if (comb[b * E + e] == 0.f) return;
  const short* A = A_b + (size_t)e * BSD + (size_t)row * D;
  const short* R = R_b + (size_t)e * BSD + (size_t)row * D;
  const float* g = g_b + (size_t)e * D;
  const float* bb = bb_b + (size_t)e * D;
  short* outp = out_b + (size_t)e * BSD;
  int d0 = lane * 4;
  short4 a4 = *reinterpret_cast<const short4*>(A + d0);
  short4 r4 = *reinterpret_cast<const short4*>(R + d0);
  float4 x = {bf2f(a4.x) + bf2f(r4.x), bf2f(a4.y) + bf2f(r4.y),
              bf2f(a4.z) + bf2f(r4.z), bf2f(a4.w) + bf2f(r4.w)};
  float mean = wave_sum64(x.x + x.y + x.z + x.w) * (1.f / D);
  float4 xm = {x.x - mean, x.y - mean, x.z - mean, x.w - mean};
  float vv = wave_sum64(xm.x * xm.x + xm.y * xm.y + xm.z * xm.z + xm.w * xm.w);
  float rs = rsqrtf(vv * (1.f / D) + EPS);
  float4 g4 = *reinterpret_cast<const float4*>(g + d0);
  float4 b4 = *reinterpret_cast<const float4*>(bb + d0);
  short4 o;
  o.x = f2bf(xm.x * rs * g4.x + b4.x);
  o.y = f2bf(xm.y * rs * g4.y + b4.y);
  o.z = f2bf(xm.z * rs * g4.z + b4.z);
  o.w = f2bf(xm.w * rs * g4.w + b4.w);
  *reinterpret_cast<short4*>(outp + (size_t)row * D + d0) = o;
}

// ---------------- ln2 + gated combine fused ----------------
template <int BF16>
__global__ __launch_bounds__(256) void ln2_combine(
    const short* __restrict__ A_b, const short* __restrict__ R_b,
    const float* __restrict__ g_b, const float* __restrict__ bb_b,
    const float* __restrict__ comb, short* __restrict__ zs,
    float* __restrict__ zf) {
  int t = threadIdx.x, lane = t & 63, w = t >> 6;
  int row = blockIdx.x * 4 + w;
  int b = row >> 7;
  int d0 = lane * 4;
  float4 z4 = {0.f, 0.f, 0.f, 0.f};
  for (int e = 0; e < E; ++e) {
    float c = comb[b * E + e];
    if (c == 0.f) continue;  // wave-uniform branch
    const short* A = A_b + (size_t)e * BSD + (size_t)row * D;
    const short* R = R_b + (size_t)e * BSD + (size_t)row * D;
    short4 a4 = *reinterpret_cast<const short4*>(A + d0);
    short4 r4 = *reinterpret_cast<const short4*>(R + d0);
    float4 x = {bf2f(a4.x) + bf2f(r4.x), bf2f(a4.y) + bf2f(r4.y),
                bf2f(a4.z) + bf2f(r4.z), bf2f(a4.w) + bf2f(r4.w)};
    float mean = wave_sum64(x.x + x.y + x.z + x.w) * (1.f / D);
    float4 xm = {x.x - mean, x.y - mean, x.z - mean, x.w - mean};
    float vv =
        wave_sum64(xm.x * xm.x + xm.y * xm.y + xm.z * xm.z + xm.w * xm.w);
    float rs = rsqrtf(vv * (1.f / D) + EPS);
    float4 g4 = *reinterpret_cast<const float4*>(g_b + (size_t)e * D + d0);
    float4 b4 = *reinterpret_cast<const float4*>(bb_b + (size_t)e * D + d0);
    z4.x += c * (xm.x * rs * g4.x + b4.x);
    z4.y += c * (xm.y * rs * g4.y + b4.y);
    z4.z += c * (xm.z * rs * g4.z + b4.z);
    z4.w += c * (xm.w * rs * g4.w + b4.w);
  }
  if (BF16) {
    int col = d0;
    int xv = (row >> 1) & 3;
    int colp = (col & ~24) | ((((col >> 3) & 3) ^ xv) << 3);
    short4 o;
    o.x = f2bf(z4.x); o.y = f2bf(z4.y); o.z = f2bf(z4.z); o.w = f2bf(z4.w);
    *reinterpret_cast<short4*>(zs + (size_t)row * 256 + colp) = o;
  } else {
    *reinterpret_cast<float4*>(zf + (size_t)row * D + d0) = z4;
  }
}

// ---------------- attention: single-pass (no max), thread per query row ----
// exp without max-subtraction: softmax is shift-invariant and |s|<~3 here.
__global__ __launch_bounds__(128) void attn2_kernel(
    const short* __restrict__ Qb, const short* __restrict__ Kb,
    const short* __restrict__ Vb, short* __restrict__ Cb,
    const float* __restrict__ comb) {
  int e = blockIdx.y;
  int bh = blockIdx.x;
  int b = bh >> 3, h = bh & 7;
  if (comb[b * E + e] == 0.f) return;
  const short* Q = Qb + (size_t)e * BSD;
  const short* K = Kb + (size_t)e * BSD;
  const short* Vv = Vb + (size_t)e * BSD;
  short* C = Cb + (size_t)e * BSD;
  __shared__ float Ks[S][36];
  __shared__ float Vs[S][36];
  int t = threadIdx.x;
  const short* kbp = K + ((size_t)(b * S + t)) * D + h * HD;
  const short* vbp = Vv + ((size_t)(b * S + t)) * D + h * HD;
#pragma unroll
  for (int j = 0; j < 4; ++j) {
    short8v k8 = *reinterpret_cast<const short8v*>(kbp + j * 8);
    short8v v8 = *reinterpret_cast<const short8v*>(vbp + j * 8);
#pragma unroll
    for (int c = 0; c < 8; ++c) {
      Ks[t][j * 8 + c] = bf2f(k8[c]);
      Vs[t][j * 8 + c] = bf2f(v8[c]);
    }
  }
  float4 qv[8];
  const short* qp = Q + ((size_t)(b * S + t)) * D + h * HD;
#pragma unroll
  for (int j = 0; j < 4; ++j) {
    short8v q8 = *reinterpret_cast<const short8v*>(qp + j * 8);
    qv[j * 2] = (float4){bf2f(q8[0]), bf2f(q8[1]), bf2f(q8[2]), bf2f(q8[3])};
    qv[j * 2 + 1] =
        (float4){bf2f(q8[4]), bf2f(q8[5]), bf2f(q8[6]), bf2f(q8[7])};
  }
  __syncthreads();
  const float scale = 0.17677669529663687f;  // 1/sqrt(32)
  float se = 0.f;
  float4 cx[8];
#pragma unroll
  for (int j = 0; j < 8; ++j) cx[j] = (float4){0.f, 0.f, 0.f, 0.f};
  for (int k = 0; k < S; ++k) {
    float s = 0.f;
#pragma unroll
    for (int j = 0; j < 8; ++j) {
      float4 k4 = *reinterpret_cast<const float4*>(&Ks[k][j * 4]);
      s += qv[j].x * k4.x + qv[j].y * k4.y + qv[j].z * k4.z + qv[j].w * k4.w;
    }
    float p = __expf(s * scale);
    se += p;
#pragma unroll
    for (int j = 0; j < 8; ++j) {
      float4 v4 = *reinterpret_cast<const float4*>(&Vs[k][j * 4]);
      cx[j].x += p * v4.x; cx[j].y += p * v4.y;
      cx[j].z += p * v4.z; cx[j].w += p * v4.w;
    }
  }
  float inv = 1.f / se;
  short* cp = C + ((size_t)(b * S + t)) * D + h * HD;
#pragma unroll
  for (int j = 0; j < 8; ++j) {
    short4 o;
    o.x = f2bf(cx[j].x * inv); o.y = f2bf(cx[j].y * inv);
    o.z = f2bf(cx[j].z * inv); o.w = f2bf(cx[j].w * inv);
    *reinterpret_cast<short4*>(cp + j * 4) = o;
  }
}

// ---------------- GEMM v2 body (BM=128): A LDS stage, B global_load_lds ----
template <int ACT, int K, int Nc, int ABF16, int OBF16>
__device__ __forceinline__ void gemm2_body(
    const char* __restrict__ Ag, const short* __restrict__ Gg,
    const float* __restrict__ bias, char* __restrict__ outp, int row0,
    int col0) {
  __shared__ short Al[128 * 40];
  __shared__ short Bl[128 * 32];
  const int t = threadIdx.x;
  const int lane = t & 63;
  const int w = t >> 6;
  const int wr = w >> 1, wc = w & 1;
  const int lrow = lane & 15;
  const int g = lane >> 4;
  const int lkoff = g * 8;                         // A frag k-half
  const int koff = (g ^ ((lrow >> 1) & 3)) << 3;   // B frag (swizzled)
  const char* Gb = (const char*)Gg;
  char* Bb = (char*)Bl;
  const int srow = t >> 2, sgrp = t & 3;
  const int woff = w * 1024;

  f32x4 acc[4][4];
#pragma unroll
  for (int m = 0; m < 4; ++m)
#pragma unroll
    for (int n = 0; n < 4; ++n) acc[m][n] = (f32x4){0.f, 0.f, 0.f, 0.f};

  for (int k0 = 0; k0 < K; k0 += 32) {
#pragma unroll
    for (int i = 0; i < 2; ++i) {
      int row = i * 64 + srow;
      gload16(Gb + (size_t)(col0 + row) * (K * 2) + (k0 >> 5) * 64 + sgrp * 16,
              Bb + i * 4096 + woff);
    }
    if (ABF16) {
      int row = t >> 1, c0 = (t & 1) * 2;
#pragma unroll
      for (int c = 0; c < 2; ++c) {
        short8v v = *reinterpret_cast<const short8v*>(
            (const short*)Ag + (size_t)(row0 + row) * K + k0 + (c0 + c) * 8);
        *reinterpret_cast<short8v*>(&Al[row * 40 + (c0 + c) * 8]) = v;
      }
    } else {
#pragma unroll
      for (int j = 0; j < 4; ++j) {
        int id = t + 256 * j;
        int row = id >> 3, s4 = id & 7;
        float4 a4 = *reinterpret_cast<const float4*>(
            (const float*)Ag + (size_t)(row0 + row) * K + k0 + s4 * 4);
        short4 p;
        p.x = f2bf(a4.x); p.y = f2bf(a4.y); p.z = f2bf(a4.z); p.w = f2bf(a4.w);
        *reinterpret_cast<short4*>(&Al[row * 40 + s4 * 4]) = p;
      }
    }
    __syncthreads();
    short8v af[4], bfv[4];
#pragma unroll
    for (int m = 0; m < 4; ++m)
      af[m] = *reinterpret_cast<const short8v*>(
          &Al[(wr * 64 + m * 16 + lrow) * 40 + lkoff]);
#pragma unroll
    for (int n = 0; n < 4; ++n)
      bfv[n] = *reinterpret_cast<const short8v*>(
          &Bl[(wc * 64 + n * 16 + lrow) * 32 + koff]);
#pragma unroll
    for (int m = 0; m < 4; ++m)
#pragma unroll
      for (int n = 0; n < 4; ++n)
        acc[m][n] = __builtin_amdgcn_mfma_f32_16x16x32_bf16(
            af[m], bfv[n], acc[m][n], 0, 0, 0);
    __syncthreads();
  }
#pragma unroll
  for (int n = 0; n < 4; ++n) {
    int col = col0 + wc * 64 + n * 16 + lrow;
    float bc = bias[col];
#pragma unroll
    for (int m = 0; m < 4; ++m) {
      int rbase = row0 + wr * 64 + m * 16 + g * 4;
      f32x4 v = acc[m][n];
#pragma unroll
      for (int r = 0; r < 4; ++r) {
        float o = v[r] + bc;
        if (ACT == 1) o = gelu_exact(o);
        if (OBF16)
          ((short*)outp)[(size_t)(rbase + r) * Nc + col] = f2bf(o);
        else
          ((float*)outp)[(size_t)(rbase + r) * Nc + col] = o;
      }
    }
  }
}

// ---------------- GEMM v2 body (BM=64) ----------------
template <int ACT, int K, int Nc, int ABF16, int OBF16>
__device__ __forceinline__ void gemm2_body64(
    const char* __restrict__ Ag, const short* __restrict__ Gg,
    const float* __restrict__ bias, char* __restrict__ outp, int row0,
    int col0) {
  __shared__ short Al[64 * 40];
  __shared__ short Bl[128 * 32];
  const int t = threadIdx.x;
  const int lane = t & 63;
  const int w = t >> 6;          // 0..3 -> 32-col group
  const int lrow = lane & 15;
  const int g = lane >> 4;
  const int lkoff = g * 8;
  const int koff = (g ^ ((lrow >> 1) & 3)) << 3;
  const char* Gb = (const char*)Gg;
  char* Bb = (char*)Bl;
  const int srow = t >> 2, sgrp = t & 3;
  const int woff = w * 1024;

  f32x4 acc[4][2];
#pragma unroll
  for (int m = 0; m < 4; ++m)
#pragma unroll
    for (int n = 0; n < 2; ++n) acc[m][n] = (f32x4){0.f, 0.f, 0.f, 0.f};

  for (int k0 = 0; k0 < K; k0 += 32) {
#pragma unroll
    for (int i = 0; i < 2; ++i) {
      int row = i * 64 + srow;
      gload16(Gb + (size_t)(col0 + row) * (K * 2) + (k0 >> 5) * 64 + sgrp * 16,
              Bb + i * 4096 + woff);
    }
    if (ABF16) {
      int row = t >> 2, seg = t & 3;
      short8v v = *reinterpret_cast<const short8v*>(
          (const short*)Ag + (size_t)(row0 + row) * K + k0 + seg * 8);
      *reinterpret_cast<short8v*>(&Al[row * 40 + seg * 8]) = v;
    } else {
#pragma unroll
      for (int j = 0; j < 2; ++j) {
        int id = t + 256 * j;
        int row = id >> 3, s4 = id & 7;
        float4 a4 = *reinterpret_cast<const float4*>(
            (const float*)Ag + (size_t)(row0 + row) * K + k0 + s4 * 4);
        short4 p;
        p.x = f2bf(a4.x); p.y = f2bf(a4.y); p.z = f2bf(a4.z); p.w = f2bf(a4.w);
        *reinterpret_cast<short4*>(&Al[row * 40 + s4 * 4]) = p;
      }
    }
    __syncthreads();
    short8v af[4], bfv[2];
#pragma unroll
    for (int m = 0; m < 4; ++m)
      af[m] = *reinterpret_cast<const short8v*>(
          &Al[(m * 16 + lrow) * 40 + lkoff]);
#pragma unroll
    for (int n = 0; n < 2; ++n)
      bfv[n] = *reinterpret_cast<const short8v*>(
          &Bl[(w * 32 + n * 16 + lrow) * 32 + koff]);
#pragma unroll
    for (int m = 0; m < 4; ++m)
#pragma unroll
      for (int n = 0; n < 2; ++n)
        acc[m][n] = __builtin_amdgcn_mfma_f32_16x16x32_bf16(
            af[m], bfv[n], acc[m][n], 0, 0, 0);
    __syncthreads();
  }
#pragma unroll
  for (int n = 0; n < 2; ++n) {
    int col = col0 + w * 32 + n * 16 + lrow;
    float bc = bias[col];
#pragma unroll
    for (int m = 0; m < 4; ++m) {
      int rbase = row0 + m * 16 + g * 4;
      f32x4 v = acc[m][n];
#pragma unroll
      for (int r = 0; r < 4; ++r) {
        float o = v[r] + bc;
        if (ACT == 1) o = gelu_exact(o);
        if (OBF16)
          ((short*)outp)[(size_t)(rbase + r) * Nc + col] = f2bf(o);
        else
          ((float*)outp)[(size_t)(rbase + r) * Nc + col] = o;
      }
    }
  }
}

// generic per-expert GEMMs
template <int ACT, int K, int Nc, int ABF16, int OBF16>
__global__ __launch_bounds__(256) void gemm2_e(
    const char* __restrict__ Ab, const short* __restrict__ Gbase,
    const float* __restrict__ biasb, char* __restrict__ outb,
    const float* __restrict__ comb, size_t aStrB, size_t oStrB, int bStr) {
  int e = blockIdx.z;
  int row0 = blockIdx.y * 128;
  int col0 = blockIdx.x * 128;
  if (comb[(row0 >> 7) * E + e] == 0.f) return;
  gemm2_body<ACT, K, Nc, ABF16, OBF16>(
      Ab + (size_t)e * aStrB, Gbase + (size_t)e * GW_STRIDE,
      biasb + (size_t)e * bStr, outb + (size_t)e * oStrB, row0, col0);
}

template <int ACT, int K, int Nc, int ABF16, int OBF16>
__global__ __launch_bounds__(256) void gemm2b64_e(
    const char* __restrict__ Ab, const short* __restrict__ Gbase,
    const float* __restrict__ biasb, char* __restrict__ outb,
    const float* __restrict__ comb, size_t aStrB, size_t oStrB, int bStr) {
  int e = blockIdx.z;
  int row0 = blockIdx.y * 64;
  int col0 = blockIdx.x * 128;
  if (comb[(row0 >> 7) * E + e] == 0.f) return;
  gemm2_body64<ACT, K, Nc, ABF16, OBF16>(
      Ab + (size_t)e * aStrB, Gbase + (size_t)e * GW_STRIDE,
      biasb + (size_t)e * bStr, outb + (size_t)e * oStrB, row0, col0);
}

// fused QKV v2 (bf16 A, bf16 out)
__global__ __launch_bounds__(256) void qkv2_e(
    const short* __restrict__ h0b, const short* __restrict__ Gw,
    const float* __restrict__ bqb, const float* __restrict__ bkb,
    const float* __restrict__ bvb, short* __restrict__ qb,
    short* __restrict__ kb, short* __restrict__ vb,
    const float* __restrict__ comb) {
  int e = blockIdx.z;
  int which = blockIdx.x >> 1;
  int col0 = (blockIdx.x & 1) * 128;
  int row0 = blockIdx.y * 128;
  if (comb[(row0 >> 7) * E + e] == 0.f) return;
  const short* G = Gw + (size_t)e * GW_STRIDE + (size_t)which * 65536;
  const float* bias =
      (which == 0 ? bqb : which == 1 ? bkb : bvb) + (size_t)e * D;
  short* outp = (which == 0 ? qb : which == 1 ? kb : vb) + (size_t)e * BSD;
  gemm2_body<0, D, D, 1, 1>((const char*)(h0b + (size_t)e * BSD), G, bias,
                            (char*)outp, row0, col0);
}

// ---------------- fallback fp32-W GEMM (head fallback only) ----------------
template <int ACT, int K, int Nc>
__device__ __forceinline__ void gemm_body(
    const float* __restrict__ Ag, const float* __restrict__ Wg,
    const float* __restrict__ bias, float* __restrict__ outp, int row0,
    int col0) {
  __shared__ short Al[128 * 40];
  __shared__ short Bl[128 * 40];
  const int t = threadIdx.x;
  const int lane = t & 63;
  const int w = t >> 6;
  const int wr = w >> 1, wc = w & 1;
  const int lrow = lane & 15;
  const int lkoff = (lane >> 4) * 8;
  f32x4 acc[4][4];
#pragma unroll
  for (int m = 0; m < 4; ++m)
#pragma unroll
    for (int n = 0; n < 4; ++n) acc[m][n] = (f32x4){0.f, 0.f, 0.f, 0.f};
  const int colB = t >> 1, kh = (t & 1) * 16;
  for (int k0 = 0; k0 < K; k0 += 32) {
#pragma unroll
    for (int j = 0; j < 4; ++j) {
      int id = t + 256 * j;
      int row = id >> 3, s4 = id & 7;
      float4 a4 = *reinterpret_cast<const float4*>(
          Ag + (size_t)(row0 + row) * K + k0 + s4 * 4);
      short4 p;
      p.x = f2bf(a4.x); p.y = f2bf(a4.y); p.z = f2bf(a4.z); p.w = f2bf(a4.w);
      *reinterpret_cast<short4*>(&Al[row * 40 + s4 * 4]) = p;
    }
    {
      const float* wp = Wg + (size_t)(k0 + kh) * Nc + (col0 + colB);
      short8v v0, v1;
#pragma unroll
      for (int kk = 0; kk < 8; ++kk) v0[kk] = f2bf(wp[(size_t)kk * Nc]);
#pragma unroll
      for (int kk = 0; kk < 8; ++kk) v1[kk] = f2bf(wp[(size_t)(kk + 8) * Nc]);
      *reinterpret_cast<short8v*>(&Bl[colB * 40 + kh]) = v0;
      *reinterpret_cast<short8v*>(&Bl[colB * 40 + kh + 8]) = v1;
    }
    __syncthreads();
    short8v af[4], bfv[4];
#pragma unroll
    for (int m = 0; m < 4; ++m)
      af[m] = *reinterpret_cast<const short8v*>(
          &Al[(wr * 64 + m * 16 + lrow) * 40 + lkoff]);
#pragma unroll
    for (int n = 0; n < 4; ++n)
      bfv[n] = *reinterpret_cast<const short8v*>(
          &Bl[(wc * 64 + n * 16 + lrow) * 40 + lkoff]);
#pragma unroll
    for (int m = 0; m < 4; ++m)
#pragma unroll
      for (int n = 0; n < 4; ++n)
        acc[m][n] = __builtin_amdgcn_mfma_f32_16x16x32_bf16(
            af[m], bfv[n], acc[m][n], 0, 0, 0);
    __syncthreads();
  }
#pragma unroll
  for (int n = 0; n < 4; ++n) {
    int col = col0 + wc * 64 + n * 16 + lrow;
    float bc = bias[col];
#pragma unroll
    for (int m = 0; m < 4; ++m) {
      int rbase = row0 + wr * 64 + m * 16 + (lane >> 4) * 4;
      f32x4 v = acc[m][n];
#pragma unroll
      for (int r = 0; r < 4; ++r) {
        float o = v[r] + bc;
        if (ACT == 1) o = gelu_exact(o);
        outp[(size_t)(rbase + r) * Nc + col] = o;
      }
    }
  }
}

__global__ __launch_bounds__(256) void head_gemm(
    const float* __restrict__ Ag, const float* __restrict__ Wg,
    const float* __restrict__ bias, float* __restrict__ outp) {
  int row0 = blockIdx.x * 128;
  int col0 = blockIdx.y * 128;
  gemm_body<0, D, V>(Ag, Wg, bias, outp, row0, col0);
}

// ---------------- head GEMM v2: both sides async-staged bf16 (r9 mapping) --
__global__ __launch_bounds__(256) void head_gemm2(
    const short* __restrict__ zs, const short* __restrict__ G,
    const float* __restrict__ bias, float* __restrict__ outp) {
  __shared__ short Al[128 * 32];
  __shared__ short Bl[128 * 32];
  const int row0 = blockIdx.x * 128;  // x fastest: row tiles share W stripe
  const int col0 = blockIdx.y * 128;
  const int t = threadIdx.x;
  const int lane = t & 63, w = t >> 6;
  const int wr = w >> 1, wc = w & 1;
  const int lrow = lane & 15;
  const int g = lane >> 4;
  const int koff = (g ^ ((lrow >> 1) & 3)) << 3;
  const int srow = t >> 2, sgrp = t & 3;
  const char* zsb = (const char*)zs;
  const char* Gb = (const char*)G;
  char* Ab = (char*)Al;
  char* Bb = (char*)Bl;
  const int woff = w * 1024;

  f32x4 acc[4][4];
#pragma unroll
  for (int m = 0; m < 4; ++m)
#pragma unroll
    for (int n = 0; n < 4; ++n) acc[m][n] = (f32x4){0.f, 0.f, 0.f, 0.f};

  for (int kb = 0; kb < 8; ++kb) {
#pragma unroll
    for (int i = 0; i < 2; ++i) {
      int row = i * 64 + srow;
      gload16(zsb + (size_t)(row0 + row) * 512 + kb * 64 + sgrp * 16,
              Ab + i * 4096 + woff);
      gload16(Gb + (size_t)(col0 + row) * 512 + kb * 64 + sgrp * 16,
              Bb + i * 4096 + woff);
    }
    __syncthreads();
    short8v af[4], bfv[4];
#pragma unroll
    for (int m = 0; m < 4; ++m)
      af[m] = *reinterpret_cast<const short8v*>(
          &Al[(wr * 64 + m * 16 + lrow) * 32 + koff]);
#pragma unroll
    for (int n = 0; n < 4; ++n)
      bfv[n] = *reinterpret_cast<const short8v*>(
          &Bl[(wc * 64 + n * 16 + lrow) * 32 + koff]);
#pragma unroll
    for (int m = 0; m < 4; ++m)
#pragma unroll
      for (int n = 0; n < 4; ++n)
        acc[m][n] = __builtin_amdgcn_mfma_f32_16x16x32_bf16(
            af[m], bfv[n], acc[m][n], 0, 0, 0);
    __syncthreads();
  }
#pragma unroll
  for (int n = 0; n < 4; ++n) {
    int col = col0 + wc * 64 + n * 16 + lrow;
    float bc = bias[col];
#pragma unroll
    for (int m = 0; m < 4; ++m) {
      int rbase = row0 + wr * 64 + m * 16 + g * 4;
      f32x4 v = acc[m][n];
#pragma unroll
      for (int r = 0; r < 4; ++r)
        outp[(size_t)(rbase + r) * V + col] = v[r] + bc;
    }
  }
}

// fallback combine reading bf16 h (only used when ws too small)
__global__ __launch_bounds__(256) void combine_f32(
    const short* __restrict__ hb, const float* __restrict__ comb,
    float* __restrict__ zf) {
  size_t i = ((size_t)blockIdx.x * 256 + threadIdx.x) * 4;
  int b = (int)(i >> 15);
  float4 acc = {0.f, 0.f, 0.f, 0.f};
#pragma unroll
  for (int e2 = 0; e2 < E; ++e2) {
    float c = comb[b * E + e2];
    if (c != 0.f) {
      short4 v = *reinterpret_cast<const short4*>(hb + (size_t)e2 * BSD + i);
      acc.x += c * bf2f(v.x); acc.y += c * bf2f(v.y);
      acc.z += c * bf2f(v.z); acc.w += c * bf2f(v.w);
    }
  }
  *reinterpret_cast<float4*>(zf + i) = acc;
}

}  // namespace

extern "C" void kernel_launch(void* const* d_in, const int* in_sizes, int n_in,
                              void* d_out, int out_size, void* d_ws,
                              size_t ws_size, hipStream_t stream) {
  const float* h_t = (const float*)d_in[0];
  const float* e_task = (const float*)d_in[1];
  const float* e_layout = (const float*)d_in[2];
  const float* tok = (const float*)d_in[3];
  const float* rW1 = (const float*)d_in[4];
  const float* rb1 = (const float*)d_in[5];
  const float* rW2 = (const float*)d_in[6];
  const float* rb2 = (const float*)d_in[7];
  const float* hW = (const float*)d_in[8];
  const float* hb = (const float*)d_in[9];
  const float* pos = (const float*)d_in[10];
  const float* typ = (const float*)d_in[11];
  const float* g0 = (const float*)d_in[12];
  const float* b0 = (const float*)d_in[13];
  const float* Wq = (const float*)d_in[14];
  const float* bq = (const float*)d_in[15];
  const float* Wk = (const float*)d_in[16];
  const float* bk = (const float*)d_in[17];
  const float* Wv = (const float*)d_in[18];
  const float* bv = (const float*)d_in[19];
  const float* Wo = (const float*)d_in[20];
  const float* bo = (const float*)d_in[21];
  const float* g1 = (const float*)d_in[22];
  const float* b1 = (const float*)d_in[23];
  const float* Wf1 = (const float*)d_in[24];
  const float* bf1 = (const float*)d_in[25];
  const float* Wf2 = (const float*)d_in[26];
  const float* bf2 = (const float*)d_in[27];
  const float* g2 = (const float*)d_in[28];
  const float* b2 = (const float*)d_in[29];
  const float* headW = (const float*)d_in[30];
  const float* headb = (const float*)d_in[31];
  const int* topk = (const int*)d_in[32];

  float* out = (float*)d_out;
  float* gp_out = out + (size_t)B * S * V;  // gate_probs tail of d_out

  // bf16 scratch in the logits region of d_out (~58 MB < 524 MB; all dead
  // before head GEMM overwrites it).
  short* h0s = (short*)out;               // [E][B*S, D]
  short* qs = h0s + (size_t)E * BSD;
  short* ks = qs + (size_t)E * BSD;
  short* vs = ks + (size_t)E * BSD;
  short* ctxs = vs + (size_t)E * BSD;
  short* fbh = ctxs + (size_t)E * BSD;    // [E][B*S, FF]
  short* Gw = fbh + (size_t)E * BSF;      // 7.9 MB expert weights

  // d_ws: G_head bf16 | comb | gp | zs bf16  (18.5 MB, proven)
  float* wsf = (float*)d_ws;
  short* Ghead = (short*)d_ws;              // 16,384,000 B
  float* comb = wsf + 4096000;
  float* gp = comb + 256;
  short* zs = (short*)(wsf + 4096512);      // 2,097,152 B
  size_t need = (size_t)4096512 * 4 + (size_t)4096 * 256 * 2;
  bool fast_head = ws_size >= need;
  if (!fast_head) {
    comb = wsf;
    gp = comb + 256;
  }
  float* zf = gp + 256;  // fp32 z for head fallback only

  // weight pre-passes
  if (fast_head)
    prep_w<<<dim3(V / 64, 4, 1), 256, 0, stream>>>(headW, Ghead, 256, V, 0, 0);
  prep_experts<<<dim3(16, 16, E * 6), 256, 0, stream>>>(Wq, Wk, Wv, Wo, Wf1,
                                                        Wf2, Gw);

  router1_kernel<<<B, HID, 0, stream>>>(h_t, e_task, e_layout, rW1, rb1, rW2,
                                        rb2, hW, hb, gp, gp_out);
  router2_kernel<<<1, 64, 0, stream>>>(gp, topk, comb);

  dim3 gLN(B * S / 4, E);
  embed_ln_w<<<gLN, 256, 0, stream>>>(h_t, e_task, e_layout, tok, pos, typ,
                                      g0, b0, h0s, comb);
  qkv2_e<<<dim3(6, 32, E), 256, 0, stream>>>(h0s, Gw, bq, bk, bv, qs, ks, vs,
                                             comb);
  attn2_kernel<<<dim3(B * H, E), 128, 0, stream>>>(qs, ks, vs, ctxs, comb);
  gemm2b64_e<0, 256, 256, 1, 1><<<dim3(2, 64, E), 256, 0, stream>>>(
      (const char*)ctxs, Gw + GW_O, bo, (char*)qs, comb, (size_t)BSD * 2,
      (size_t)BSD * 2, 256);
  add_ln_w<<<gLN, 256, 0, stream>>>(h0s, qs, g1, b1, ks, comb);
  gemm2_e<1, 256, 1024, 1, 1><<<dim3(8, 32, E), 256, 0, stream>>>(
      (const char*)ks, Gw + GW_F1, bf1, (char*)fbh, comb, (size_t)BSD * 2,
      (size_t)BSF * 2, FF);
  gemm2b64_e<0, 1024, 256, 1, 1><<<dim3(2, 64, E), 256, 0, stream>>>(
      (const char*)fbh, Gw + GW_F2, bf2, (char*)vs, comb, (size_t)BSF * 2,
      (size_t)BSD * 2, 256);

  if (fast_head) {
    ln2_combine<1><<<B * S / 4, 256, 0, stream>>>(ks, vs, g2, b2, comb, zs,
                                                  nullptr);
    head_gemm2<<<dim3(32, V / 128), 256, 0, stream>>>(zs, Ghead, headb, out);
  } else {
    add_ln_w<<<gLN, 256, 0, stream>>>(ks, vs, g2, b2, h0s, comb);
    combine_f32<<<BSD / 1024, 256, 0, stream>>>(h0s, comb, zf);
    head_gemm<<<dim3(32, V / 128), 256, 0, stream>>>(zf, headW, headb, out);
  }
  (void)in_sizes; (void)n_in; (void)out_size;
}